// Round 9
// baseline (633.419 us; speedup 1.0000x reference)
//
#include <hip/hip_runtime.h>
#include <hip/hip_bf16.h>

typedef short s16x8 __attribute__((ext_vector_type(8)));      // 8 bf16 (4 VGPRs)
typedef float f32x4 __attribute__((ext_vector_type(4)));
typedef float f32x16 __attribute__((ext_vector_type(16)));
typedef unsigned short us8 __attribute__((ext_vector_type(8)));

#define HE     1024
#define SEQ    4096
#define NBAT   32
#define MTOT   (NBAT * SEQ)   // 131072
#define BM     128            // rows per block
#define BN     256            // cols per block (4 n-slices)
#define KT     64             // k per tile
#define NT     16             // K tiles
#define APITCH 1040           // padded pitch per 1KB A-staging instr (4 rows)

__device__ __forceinline__ unsigned short f2bf(float f) {
    unsigned u = __builtin_bit_cast(unsigned, f);
    u += 0x7FFFu + ((u >> 16) & 1u);
    return (unsigned short)(u >> 16);
}

__device__ __forceinline__ float tanh_fast(float x) {
    float e = __expf(2.0f * x);
    return 1.0f - 2.0f / (e + 1.0f);
}

__device__ __forceinline__ void gload_lds16(const void* g, void* l) {
    __builtin_amdgcn_global_load_lds(
        (const __attribute__((address_space(1))) unsigned int*)g,
        (__attribute__((address_space(3))) unsigned int*)l,
        16, 0, 0);
}

// 8 fp32 -> s16x8 bf16 via v_cvt_pk_bf16_f32 (RNE)
__device__ __forceinline__ s16x8 cvt8(f32x4 a, f32x4 b) {
    int d0, d1, d2, d3;
    asm("v_cvt_pk_bf16_f32 %0, %1, %2" : "=v"(d0) : "v"(a[0]), "v"(a[1]));
    asm("v_cvt_pk_bf16_f32 %0, %1, %2" : "=v"(d1) : "v"(a[2]), "v"(a[3]));
    asm("v_cvt_pk_bf16_f32 %0, %1, %2" : "=v"(d2) : "v"(b[0]), "v"(b[1]));
    asm("v_cvt_pk_bf16_f32 %0, %1, %2" : "=v"(d3) : "v"(b[2]), "v"(b[3]));
    int4 r{d0, d1, d2, d3};
    return __builtin_bit_cast(s16x8, r);
}

// ---- h_proj partials
__global__ void k_hproj(const float* __restrict__ hidden, const float* __restrict__ W,
                        float* __restrict__ cpart) {
    int b = blockIdx.x >> 3, kc = blockIdx.x & 7;
    int h = threadIdx.x;
    const float* hv = hidden + (NBAT + b) * HE;   // hidden[-1]
    int k0 = kc * 128;
    float acc = 0.f;
    for (int j = 0; j < 128; ++j)
        acc = fmaf(hv[k0 + j], W[(k0 + j) * HE + h], acc);
    cpart[(b * 8 + kc) * HE + h] = acc;
}

__global__ void k_cfinal(const float* __restrict__ cpart, const float* __restrict__ b_attn,
                         float* __restrict__ c) {
    int b = blockIdx.x, h = threadIdx.x;
    float s = b_attn[h];
    #pragma unroll
    for (int kc = 0; kc < 8; ++kc) s += cpart[(b * 8 + kc) * HE + h];
    c[b * HE + h] = s;
}

// ---- pack W_e (= W_attn[He:]) into 32x32x16 MFMA B-fragment order, tiled:
// frag# within (nsl,kt) = s*8 + fc; lane l holds
//   bf16 W_e[kt*64 + s*16 + (l>>5)*8 + i][nsl*256 + fc*32 + (l&31)]
__global__ void k_pack(const float* __restrict__ W, unsigned short* __restrict__ Wp) {
    int gid = blockIdx.x * blockDim.x + threadIdx.x;   // 131072 threads
    int l = gid & 63, frag = (gid >> 6) & 31, kt = (gid >> 11) & 15, nsl = gid >> 15;
    int s = frag >> 3, fc = frag & 7;
    int krow = HE + kt * 64 + s * 16 + ((l >> 5) * 8);
    int col  = nsl * 256 + fc * 32 + (l & 31);
    us8 v;
    #pragma unroll
    for (int i = 0; i < 8; ++i) v[i] = f2bf(W[(krow + i) * HE + col]);
    *(us8*)(Wp + (long)gid * 8) = v;
}

// ---- main GEMM: 128x256 tile, 512 thr (8 waves 2Mx4N, wave 64x64, 32x32x16),
//      ZERO register VMEM in K-loop: A (fp32) and B (bf16 packed) both via
//      global_load_lds; fp32->bf16 cvt after LDS read; 1 barrier/tile,
//      full-tile prefetch distance.
__global__ __launch_bounds__(512, 1) void k_main(
    const float* __restrict__ E, const unsigned short* __restrict__ Wp,
    const float* __restrict__ C, const float* __restrict__ VW,
    float* __restrict__ spart)
{
    __shared__ __align__(16) char Ab[2][32 * APITCH];      // 2 x 32.5 KB fp32 A tile
    __shared__ __align__(16) char Bb[2][32768];            // 2 x 32 KB bf16 B frags
    __shared__ float smred[BM][4];

    const int tid  = threadIdx.x;
    const int lane = tid & 63;
    const int wv   = tid >> 6;           // 8 waves
    const int mh   = wv >> 2;            // m-half (64 rows)
    const int nq   = wv & 3;             // n-quarter (64 cols)
    const int l31  = lane & 31, lh = lane >> 5;

    // XCD-chunked swizzle: 4 n-slice siblings of a stripe adjacent on one XCD
    const int wgid = blockIdx.x;
    const int idx  = (wgid & 7) * 512 + (wgid >> 3);   // bijective, 4096 blocks
    const int nsl  = idx & 3;
    const int m0   = (idx >> 2) * BM;
    const int bb   = m0 >> 12;

    // A staging: per-lane source offset (constant): row-in-4 = l>>4, unit XOR
    const int voffA = ((lane >> 4) << 12) + ((((lane & 15) ^ ((lane >> 4) << 2))) << 4);
    const char* Ebase = (const char*)E + ((long)m0 << 12);
    const char* WpBase = (const char*)Wp + (((long)nsl * 16) << 15);

    // A read bases: row r = (mh*2+rf)*32 + l31
    //   byte = (r>>2)*APITCH + (r&3)*256 + ((u) ^ ((r&3)<<2))*16
    int ar_base[2];
    #pragma unroll
    for (int rf = 0; rf < 2; ++rf)
        ar_base[rf] = (((mh * 2 + rf) * 8 + (l31 >> 2)) * APITCH) + (l31 & 3) * 256;
    const int xr = (l31 & 3) << 2;

    f32x16 acc[2][2];
    #pragma unroll
    for (int rf = 0; rf < 2; ++rf)
        #pragma unroll
        for (int cf = 0; cf < 2; ++cf)
            #pragma unroll
            for (int e = 0; e < 16; ++e) acc[rf][cf][e] = 0.f;

#define STAGE(pb, t1) do {                                                       \
    const char* asrc_ = Ebase + ((long)(wv * 16) << 12) + ((t1) << 8) + voffA;   \
    char* adst_ = &Ab[pb][0] + wv * 4 * APITCH;                                  \
    _Pragma("unroll")                                                            \
    for (int c_ = 0; c_ < 4; ++c_)                                               \
        gload_lds16(asrc_ + ((long)c_ << 14), adst_ + c_ * APITCH);              \
    const char* bsrc_ = WpBase + ((long)(t1) << 15) + (wv << 12) + (lane << 4);  \
    char* bdst_ = &Bb[pb][0] + (wv << 12);                                       \
    _Pragma("unroll")                                                            \
    for (int c_ = 0; c_ < 4; ++c_)                                               \
        gload_lds16(bsrc_ + (c_ << 10), bdst_ + (c_ << 10));                     \
} while (0)

#define KSTEP(pb, s) do {                                                        \
    const char* Ap_ = &Ab[pb][0];                                                \
    const char* Bp_ = &Bb[pb][0];                                                \
    const int u0_ = (s) * 4 + lh * 2;                                            \
    s16x8 abf_[2], bbf_[2];                                                      \
    _Pragma("unroll")                                                            \
    for (int rf = 0; rf < 2; ++rf) {                                             \
        const int o_ = ar_base[rf] + ((u0_ ^ xr) << 4);                          \
        f32x4 v0_ = *(const f32x4*)(Ap_ + o_);                                   \
        f32x4 v1_ = *(const f32x4*)(Ap_ + o_ + 16);                              \
        abf_[rf] = cvt8(v0_, v1_);                                               \
    }                                                                            \
    _Pragma("unroll")                                                            \
    for (int cf = 0; cf < 2; ++cf)                                               \
        bbf_[cf] = *(const s16x8*)(Bp_ + ((((s) * 8 + nq * 2 + cf)) << 10)       \
                                       + (lane << 4));                           \
    __builtin_amdgcn_s_setprio(1);                                               \
    _Pragma("unroll")                                                            \
    for (int rf = 0; rf < 2; ++rf)                                               \
        _Pragma("unroll")                                                        \
        for (int cf = 0; cf < 2; ++cf)                                           \
            acc[rf][cf] = __builtin_amdgcn_mfma_f32_32x32x16_bf16(               \
                abf_[rf], bbf_[cf], acc[rf][cf], 0, 0, 0);                       \
    __builtin_amdgcn_s_setprio(0);                                               \
} while (0)

    // prologue: stage tile 0, drain
    STAGE(0, 0);
    __syncthreads();

    for (int t = 0; t < NT; ++t) {
        const int pb = t & 1;
        if (t + 1 < NT) STAGE(pb ^ 1, t + 1);   // in flight across the whole tile
        KSTEP(pb, 0);
        KSTEP(pb, 1);
        KSTEP(pb, 2);
        KSTEP(pb, 3);
        __syncthreads();                         // drains t+1 staging (full-tile slack)
    }

#undef STAGE
#undef KSTEP

    // fused epilogue: partial score over this block's 256 cols
    float cv[2], vv[2];
    #pragma unroll
    for (int cf = 0; cf < 2; ++cf) {
        int col = nsl * 256 + nq * 64 + cf * 32 + l31;
        cv[cf] = C[bb * HE + col];
        vv[cf] = VW[col];
    }
    #pragma unroll
    for (int rf = 0; rf < 2; ++rf) {
        #pragma unroll
        for (int reg = 0; reg < 16; ++reg) {
            float pS = 0.f;
            #pragma unroll
            for (int cf = 0; cf < 2; ++cf)
                pS += tanh_fast(acc[rf][cf][reg] + cv[cf]) * vv[cf];
            pS += __shfl_xor(pS, 1);
            pS += __shfl_xor(pS, 2);
            pS += __shfl_xor(pS, 4);
            pS += __shfl_xor(pS, 8);
            pS += __shfl_xor(pS, 16);
            if (l31 == 0) {
                int row = mh * 64 + rf * 32 + (reg & 3) + 8 * (reg >> 2) + 4 * lh;
                smred[row][nq] = pS;
            }
        }
    }
    __syncthreads();
    if (tid < BM) {
        float s = smred[tid][0] + smred[tid][1] + smred[tid][2] + smred[tid][3];
        spart[(long)nsl * MTOT + m0 + tid] = s;
    }
}

// ---- softmax over S=4096 per batch row (sums 4 col-slice partials)
__global__ void k_softmax(const float* __restrict__ spart, float* __restrict__ out) {
    __shared__ float red[16];
    __shared__ float red2[16];
    int b = blockIdx.x, tid = threadIdx.x;
    float v[4];
    float mx = -1e30f;
    #pragma unroll
    for (int j = 0; j < 4; ++j) {
        long i = (long)b * SEQ + tid + j * 1024;
        v[j] = spart[i] + spart[MTOT + i] + spart[2L * MTOT + i] + spart[3L * MTOT + i];
        mx = fmaxf(mx, v[j]);
    }
    #pragma unroll
    for (int off = 32; off; off >>= 1) mx = fmaxf(mx, __shfl_xor(mx, off));
    if ((tid & 63) == 0) red[tid >> 6] = mx;
    __syncthreads();
    mx = red[0];
    #pragma unroll
    for (int i = 1; i < 16; ++i) mx = fmaxf(mx, red[i]);
    float sum = 0.f;
    #pragma unroll
    for (int j = 0; j < 4; ++j) { v[j] = expf(v[j] - mx); sum += v[j]; }
    #pragma unroll
    for (int off = 32; off; off >>= 1) sum += __shfl_xor(sum, off);
    if ((tid & 63) == 0) red2[tid >> 6] = sum;
    __syncthreads();
    sum = 0.f;
    #pragma unroll
    for (int i = 0; i < 16; ++i) sum += red2[i];
    float inv = 1.0f / sum;
    #pragma unroll
    for (int j = 0; j < 4; ++j) out[b * SEQ + tid + j * 1024] = v[j] * inv;
}

extern "C" void kernel_launch(void* const* d_in, const int* in_sizes, int n_in,
                              void* d_out, int out_size, void* d_ws, size_t ws_size,
                              hipStream_t stream)
{
    const float* hidden = (const float*)d_in[0];
    const float* enc    = (const float*)d_in[1];
    const float* W      = (const float*)d_in[2];
    const float* b_attn = (const float*)d_in[3];
    const float* v_w    = (const float*)d_in[4];
    float* out          = (float*)d_out;

    char* ws = (char*)d_ws;
    unsigned short* Wp = (unsigned short*)(ws);                        // 2 MB packed bf16 W_e
    float* cpart       = (float*)(ws + (2u << 20));                    // 1 MB
    float* Cc          = (float*)(ws + (3u << 20));                    // 128 KB
    float* spart       = (float*)(ws + (3u << 20) + (128u << 10));     // 4 x 512 KB partials

    k_pack   <<<512, 256,  0, stream>>>(W, Wp);
    k_hproj  <<<256, 1024, 0, stream>>>(hidden, W, cpart);
    k_cfinal <<<32,  1024, 0, stream>>>(cpart, b_attn, Cc);
    k_main   <<<4096, 512, 0, stream>>>(enc, Wp, Cc, v_w, spart);
    k_softmax<<<32,  1024, 0, stream>>>(spart, out);
}